// Round 2
// baseline (2322.953 us; speedup 1.0000x reference)
//
#include <hip/hip_runtime.h>

// PopulationSNN: 3-layer LIF SNN, T=100 sequential steps, B=2048.
// R4: NTH 512->1024 (4 waves/SIMD instead of 2; R3 was latency-stalled at
//     VALUBusy 65% with 1 block/CU by 127.5KB LDS). Row-split (rh) halves
//     per-thread work; W1 L2 traffic unchanged (still 256 blocks).
//     Transpose uses 128-row tiles for 512B store chunks.
// Kept from R3: two timesteps per W1 pass; GEMM2 spike-sparsity skip
//     (wave-uniform, bit-exact); GEMM3 s2any skip.

#define T_STEPS 100
#define BB      2048
#define N_IN    512
#define H1S     512
#define H2S     256
#define NOUT    5
#define BT      8
#define NTH     1024

// ---- transpose x:(B*N, T) -> xt:(T, B*N), 128-row tiles ----
__global__ __launch_bounds__(256)
void transpose_kernel(const float* __restrict__ x, float* __restrict__ xt) {
    __shared__ float tile[128 * 101];   // 51.7KB -> 2 blocks/CU
    const long i0 = (long)blockIdx.x * 128;
    const float4* src = (const float4*)(x + i0 * T_STEPS);
    for (int f = threadIdx.x; f < 3200; f += 256) {
        float4 v = src[f];
        int i  = f / 25;
        int t4 = (f % 25) * 4;
        float* d = &tile[i * 101 + t4];
        d[0] = v.x; d[1] = v.y; d[2] = v.z; d[3] = v.w;
    }
    __syncthreads();
    const int lane = threadIdx.x & 127;
    const int tg   = threadIdx.x >> 7;   // 0/1
    for (int t = tg; t < T_STEPS; t += 2) {
        xt[(long)t * (BB * N_IN) + i0 + lane] = tile[lane * 101 + t];
    }
}

// ---- generic 32x32 transpose: dst[c*R + r] = src[r*C + c] ----
__global__ __launch_bounds__(256)
void wtrans_kernel(const float* __restrict__ src, float* __restrict__ dst,
                   int R, int C) {
    __shared__ float tl[32][33];
    const int c0 = blockIdx.x * 32, r0 = blockIdx.y * 32;
    const int lx = threadIdx.x & 31, ly = threadIdx.x >> 5;
    for (int i = ly; i < 32; i += 8)
        tl[i][lx] = src[(size_t)(r0 + i) * C + c0 + lx];
    __syncthreads();
    for (int i = ly; i < 32; i += 8)
        dst[(size_t)(c0 + i) * R + r0 + lx] = tl[lx][i];
}

__device__ __forceinline__ void lif4(float4 h, float4& v, float4& sp) {
    v.x += (h.x - v.x) * 0.5f; v.y += (h.y - v.y) * 0.5f;
    v.z += (h.z - v.z) * 0.5f; v.w += (h.w - v.w) * 0.5f;
    sp.x = (v.x >= 1.0f) ? 1.0f : 0.0f; if (v.x >= 1.0f) v.x = 0.0f;
    sp.y = (v.y >= 1.0f) ? 1.0f : 0.0f; if (v.y >= 1.0f) v.y = 0.0f;
    sp.z = (v.z >= 1.0f) ? 1.0f : 0.0f; if (v.z >= 1.0f) v.z = 0.0f;
    sp.w = (v.w >= 1.0f) ? 1.0f : 0.0f; if (v.w >= 1.0f) v.w = 0.0f;
}

#define G2Q(QI, C) { float4 w = wk[QI * 64];                                    \
    _Pragma("unroll") for (int r = 0; r < 4; ++r) {                             \
        acc2[r].x += a[r].C * w.x; acc2[r].y += a[r].C * w.y;                   \
        acc2[r].z += a[r].C * w.z; acc2[r].w += a[r].C * w.w; } }

template <bool USE_XT>
__global__ __launch_bounds__(NTH, 4)
void snn_kernel(const float* __restrict__ xsrc,
                const float* __restrict__ W1t,   // (512 k, 512 j)
                const float* __restrict__ b1,
                const float* __restrict__ W2t,   // (512 k, 256 j)
                const float* __restrict__ b2,
                const float* __restrict__ Wo,    // (5, 256)
                const float* __restrict__ bo,
                float* __restrict__ out)
{
    __shared__ float scratch[16384];             // 64KB reduce scratch
    __shared__ float xb[2][4096];                // 32KB x tiles (t0, t1)
    __shared__ float s1[4096];                   // 16KB spikes L1
    __shared__ float s2[2048];                   // 8KB  spikes L2
    __shared__ float woL[1280];                  // 5KB  Wo cache
    __shared__ float part[320];
    __shared__ unsigned long long flg1[128];     // per-quad spike flags (8 rows x byte)
    __shared__ int s2any;

    const int tid = threadIdx.x;
    const int b0  = blockIdx.x * BT;

    // GEMM1 roles: j=jg1*4; k in [kg1*128,+128); rows rh1*4..+4
    const int jg1 = tid & 127, kg1 = (tid >> 7) & 3, rh1 = tid >> 9;
    // GEMM2 roles: j=jg2*4; k in [kg2*64,+64); rows rh2*4..+4
    const int jg2 = tid & 63, rh2 = (tid >> 6) & 1, kg2 = tid >> 7;
    // reduce1: row rr, j4-col c1 (1024 = 8 rows x 128 cols)
    const int rr = tid >> 7, c1 = tid & 127;
    // reduce2 (tid<512): row rr2, j4-col c2
    const int rr2 = tid >> 6, c2 = tid & 63;
    // GEMM3 roles
    const int ro = tid >> 3, cc3 = tid & 7;
    const int r3 = ro / 5, o3 = ro - 5 * r3;     // valid tid<320
    const int rf = tid / 5, of = tid - 5 * rf;   // valid tid<40

    for (int i = tid; i < NOUT * H2S; i += NTH) woL[i] = Wo[i];
    if (tid == 0) s2any = 0;

    float4 b1v, b2v;
    b1v = *(const float4*)&b1[c1 * 4];
    b2v = *(const float4*)&b2[c2 * 4];
    float4 v1 = make_float4(0.f,0.f,0.f,0.f), v2 = v1;
    float vo = 0.0f, osum = 0.0f, bor = (tid < 40) ? bo[of] : 0.0f;

    float4* sc4  = (float4*)scratch;
    float4* xb40 = (float4*)xb[0];
    float4* xb41 = (float4*)xb[1];
    float4* s1f4 = (float4*)s1;
    float4* s2f4 = (float4*)s2;
    const float4* w1p = ((const float4*)W1t) + jg1;  // row k: k*128 float4
    const float4* w2p = ((const float4*)W2t) + jg2;  // row k: k*64 float4

    for (int t0 = 0; t0 < T_STEPS; t0 += 2) {
        // ---- stage two x tiles (one float4 per thread per tile) ----
        if (USE_XT) {
            const float4* src0 = (const float4*)(xsrc + (size_t)t0 * (BB * N_IN)
                                                 + (size_t)b0 * N_IN);
            const float4* src1 = src0 + (BB * N_IN) / 4;
            xb40[tid] = src0[tid];
            xb41[tid] = src1[tid];
        } else {
#pragma unroll
            for (int e = 0; e < 4; ++e) {
                int i = tid + e * NTH;
                float2 v = *(const float2*)&xsrc[((size_t)(b0 + (i >> 9)) * N_IN
                                                 + (i & 511)) * T_STEPS + t0];
                xb[0][i] = v.x; xb[1][i] = v.y;
            }
        }
        __syncthreads();                                      // A

        // ---- GEMM1 over BOTH timesteps: one W1 pass, two acc sets ----
        float4 acc0[4], acc1[4];
#pragma unroll
        for (int r = 0; r < 4; ++r) {
            acc0[r] = make_float4(0.f,0.f,0.f,0.f);
            acc1[r] = make_float4(0.f,0.f,0.f,0.f);
        }
        {
            const int kb4 = kg1 * 32;
            const int rb  = rh1 * 4;
#pragma unroll 1
            for (int k4 = 0; k4 < 32; ++k4) {
                float4 a0[4], a1[4];
#pragma unroll
                for (int r = 0; r < 4; ++r) {
                    a0[r] = xb40[(rb + r) * 128 + kb4 + k4];   // wave-uniform bcast
                    a1[r] = xb41[(rb + r) * 128 + kb4 + k4];
                }
                const float4* wk = w1p + (size_t)(kb4 + k4) * 512;
#define G1Q(QI, C) { float4 w = wk[QI * 128];                                   \
    _Pragma("unroll") for (int r = 0; r < 4; ++r) {                             \
        acc0[r].x += a0[r].C * w.x; acc0[r].y += a0[r].C * w.y;                 \
        acc0[r].z += a0[r].C * w.z; acc0[r].w += a0[r].C * w.w; }               \
    _Pragma("unroll") for (int r = 0; r < 4; ++r) {                             \
        acc1[r].x += a1[r].C * w.x; acc1[r].y += a1[r].C * w.y;                 \
        acc1[r].z += a1[r].C * w.z; acc1[r].w += a1[r].C * w.w; } }
                G1Q(0, x) G1Q(1, y) G1Q(2, z) G1Q(3, w)
#undef G1Q
            }
        }

        // ---- per-timestep tail (tau unrolled -> static acc selection) ----
#pragma unroll
        for (int tau = 0; tau < 2; ++tau) {
            // partials -> scratch; last scratch read was pre-F. safe.
#pragma unroll
            for (int r = 0; r < 4; ++r)
                sc4[(kg1 * 8 + rh1 * 4 + r) * 128 + jg1] = tau ? acc1[r] : acc0[r];
            __syncthreads();                                  // C

            // ---- reduce1 + LIF1 -> s1 + quad spike flags ----
            {
                float4 h = b1v;
#pragma unroll
                for (int kg = 0; kg < 4; ++kg) {
                    float4 p = sc4[(kg * 8 + rr) * 128 + c1];
                    h.x += p.x; h.y += p.y; h.z += p.z; h.w += p.w;
                }
                float4 sp; lif4(h, v1, sp);
                s1f4[rr * 128 + c1] = sp;
                ((unsigned char*)flg1)[c1 * 8 + rr] =
                    (sp.x + sp.y + sp.z + sp.w > 0.0f) ? 1 : 0;
            }
            __syncthreads();                                  // D
            if (tid == 0) s2any = 0;   // prev read into regs right after F

            // ---- GEMM2 with wave-uniform sparsity skip ----
            float4 acc2[4];
#pragma unroll
            for (int r = 0; r < 4; ++r) acc2[r] = make_float4(0.f,0.f,0.f,0.f);
            {
                const int kq0 = kg2 * 16;
                const int rb2 = rh2 * 4;
#pragma unroll 1
                for (int k4 = 0; k4 < 16; ++k4) {
                    const int kb = kq0 + k4;
                    // kg2/rh2 wave-uniform -> uniform branch; skipped quads
                    // contribute exactly 0 -> bit-exact.
                    if (flg1[kb] != 0ULL) {
                        float4 a[4];
#pragma unroll
                        for (int r = 0; r < 4; ++r) a[r] = s1f4[(rb2 + r) * 128 + kb];
                        const float4* wk = w2p + (size_t)kb * 256;
                        G2Q(0, x) G2Q(1, y) G2Q(2, z) G2Q(3, w)
                    }
                }
            }
            // scratch last read pre-D; safe without extra barrier
#pragma unroll
            for (int r = 0; r < 4; ++r)
                sc4[(kg2 * 8 + rh2 * 4 + r) * 64 + jg2] = acc2[r];
            __syncthreads();                                  // E

            // ---- reduce2 + LIF2 -> s2 (+ any-spike flag) ----
            if (tid < 512) {
                float4 h = b2v;
#pragma unroll
                for (int kg = 0; kg < 8; ++kg) {
                    float4 p = sc4[(kg * 8 + rr2) * 64 + c2];
                    h.x += p.x; h.y += p.y; h.z += p.z; h.w += p.w;
                }
                float4 sp; lif4(h, v2, sp);
                s2f4[rr2 * 64 + c2] = sp;
                if (sp.x + sp.y + sp.z + sp.w > 0.0f) s2any = 1;
            }
            __syncthreads();                                  // F
            const int sk3 = s2any;   // block-uniform

            // ---- GEMM3 (only if any layer-2 spike) ----
            if (sk3) {
                if (tid < 320) {
                    const float4* sp2 = s2f4 + r3 * 64 + cc3 * 8;
                    const float4* wo4 = ((const float4*)woL) + o3 * 64 + cc3 * 8;
                    float p = 0.0f;
#pragma unroll
                    for (int k = 0; k < 8; ++k) {
                        float4 a = sp2[k], w = wo4[k];
                        p += a.x * w.x + a.y * w.y + a.z * w.z + a.w * w.w;
                    }
                    part[tid] = p;
                }
                __syncthreads();                              // G
            }
            if (tid < 40) {
                float o_cur = bor;
                if (sk3) {
#pragma unroll
                    for (int i = 0; i < 8; ++i) o_cur += part[tid * 8 + i];
                }
                float v = vo + (o_cur - vo) * 0.5f;
                if (v >= 1.0f) { osum += 1.0f; vo = 0.0f; }
                else           { vo = v; }
            }
        } // tau
    }

    if (tid < 40) out[(size_t)(b0 + rf) * NOUT + of] = osum / (float)T_STEPS;
}
#undef G2Q

extern "C" void kernel_launch(void* const* d_in, const int* in_sizes, int n_in,
                              void* d_out, int out_size, void* d_ws, size_t ws_size,
                              hipStream_t stream) {
    const float* x  = (const float*)d_in[0];
    const float* W1 = (const float*)d_in[1];
    const float* b1 = (const float*)d_in[2];
    const float* W2 = (const float*)d_in[3];
    const float* b2 = (const float*)d_in[4];
    const float* Wo = (const float*)d_in[5];
    const float* bo = (const float*)d_in[6];
    float* out = (float*)d_out;

    const size_t xt_elems = (size_t)T_STEPS * BB * N_IN;
    const size_t w1t_elems = (size_t)H1S * N_IN;
    const size_t w2t_elems = (size_t)H2S * H1S;
    const size_t full_bytes = (xt_elems + w1t_elems + w2t_elems) * sizeof(float);

    if (ws_size >= full_bytes) {
        float* xt  = (float*)d_ws;
        float* w1t = xt + xt_elems;
        float* w2t = w1t + w1t_elems;
        transpose_kernel<<<(BB * N_IN) / 128, 256, 0, stream>>>(x, xt);
        wtrans_kernel<<<dim3(N_IN / 32, H1S / 32), 256, 0, stream>>>(W1, w1t, H1S, N_IN);
        wtrans_kernel<<<dim3(H1S / 32, H2S / 32), 256, 0, stream>>>(W2, w2t, H2S, H1S);
        snn_kernel<true><<<BB / BT, NTH, 0, stream>>>(xt, w1t, b1, w2t, b2, Wo, bo, out);
    } else {
        float* w1t = (float*)d_ws;
        float* w2t = w1t + w1t_elems;
        wtrans_kernel<<<dim3(N_IN / 32, H1S / 32), 256, 0, stream>>>(W1, w1t, H1S, N_IN);
        wtrans_kernel<<<dim3(H1S / 32, H2S / 32), 256, 0, stream>>>(W2, w2t, H2S, H1S);
        snn_kernel<false><<<BB / BT, NTH, 0, stream>>>(x, w1t, b1, w2t, b2, Wo, bo, out);
    }
}

// Round 4
// 1163.979 us; speedup vs baseline: 1.9957x; 1.9957x over previous
//
#include <hip/hip_runtime.h>

// PopulationSNN R6: bf16-MFMA rewrite (R5 re-audited + per-tile GEMM2 flags).
// - GEMM1/GEMM2 on matrix cores (mfma_f32_16x16x32_bf16), M=32 tile =
//   8 batch rows x 4 timesteps (two 16x16 tiles sharing B-frags -> W1 L2
//   traffic halved vs 2-step pairing).
// - LIF in accumulator fragment layout: v-state mirrored across lane
//   halves, one shfl_xor(32) per h-reg; no reduce scratch, 3 barriers/quad.
// - Bit-exactness: output = L2-spike counts; |h2| <= ~0.3 << 1 so bf16
//   rounding of x/W1/W2 cannot flip an L2 spike; layer 3 exact fp32.
// - x pre-packed to bf16 (t_even,t_odd) u32 pairs; W1/W2 pre-converted bf16.
// - kt-XOR swizzle on LDS fragment layouts: b128 LDS ops conflict-free.
// - GEMM2 skip flags per (kt, M-tile): ~51% skip per tile at analyzed
//   L1 spike density; wave-uniform branch; skipped tile's A is exactly 0.

#define T_STEPS 100
#define BB      2048
#define N_IN    512
#define H1S     512
#define H2S     256
#define NOUT    5
#define BT      8
#define NTH     1024
#define BN      (BB * N_IN)   // 1048576

typedef __attribute__((ext_vector_type(8))) short bf16x8;
typedef __attribute__((ext_vector_type(4))) float f32x4;

__device__ __forceinline__ unsigned int bf16rne(float f) {
    unsigned int u = __float_as_uint(f);
    return (u + 0x7fffu + ((u >> 16) & 1u)) >> 16;
}

// ---- pack x:(B*N, T) fp32 -> xp:(50, B*N) u32 = (bf16 t_even | bf16 t_odd<<16) ----
__global__ __launch_bounds__(256)
void xpack_kernel(const float* __restrict__ x, unsigned int* __restrict__ xp) {
    __shared__ unsigned int tl[128][51];
    const long i0 = (long)blockIdx.x * 128;
    const float4* src = (const float4*)(x + i0 * T_STEPS);
    for (int f = threadIdx.x; f < 3200; f += 256) {   // 128 rows x 25 float4
        float4 v = src[f];
        int i = f / 25, t4 = (f % 25) * 4;
        tl[i][t4 / 2]     = bf16rne(v.x) | (bf16rne(v.y) << 16);
        tl[i][t4 / 2 + 1] = bf16rne(v.z) | (bf16rne(v.w) << 16);
    }
    __syncthreads();
    const int lane = threadIdx.x & 127;
    for (int it = 0; it < 25; ++it) {
        int t2 = it * 2 + (threadIdx.x >> 7);
        xp[(long)t2 * BN + i0 + lane] = tl[lane][t2];
    }
}

// ---- fp32 -> bf16 weight convert ----
__global__ __launch_bounds__(256)
void wconv_kernel(const float* __restrict__ w, unsigned short* __restrict__ o, int n) {
    int i = blockIdx.x * 256 + threadIdx.x;
    if (i < n) o[i] = (unsigned short)bf16rne(w[i]);
}

__device__ __forceinline__ float lifstep(float& v, float cur) {
    v = v + (cur - v) * 0.5f;
    float s = (v >= 1.0f) ? 1.0f : 0.0f;
    if (v >= 1.0f) v = 0.0f;
    return s;
}

__global__ __launch_bounds__(NTH, 4)
void snn_kernel(const unsigned int* __restrict__ xp,
                const unsigned short* __restrict__ W1b,  // [512 j][512 k] bf16
                const float* __restrict__ b1,
                const unsigned short* __restrict__ W2b,  // [256 j][512 k] bf16
                const float* __restrict__ b2,
                const float* __restrict__ Wo,            // (5,256) fp32
                const float* __restrict__ bo,
                float* __restrict__ out)
{
    // M=32 tile: m 0-15 = tile0 (t0 rows 0-7, t1 rows 8-15), m 16-31 = tile1 (t2,t3)
    __shared__ __align__(16) char xab[32768];   // A-frag layout [16 kt][2 tile][1KB], kt-XOR swz
    __shared__ __align__(16) char s1b[32768];   // same layout for GEMM2 A
    __shared__ __align__(16) float s2f[32 * 256];
    __shared__ __align__(16) float woL[NOUT * H2S];
    __shared__ float ot[160];
    __shared__ int flg2[16];                    // bit0: tile0 has spikes, bit1: tile1
    __shared__ int s2any;

    const int tid = threadIdx.x;
    const int b0  = blockIdx.x * BT;
    const int w = tid >> 6, lane = tid & 63;
    const int l15 = lane & 15, kg = lane >> 4;
    const bool glo = lane < 32;          // lower lane half (fragment rows m<8 of each tile)

    // staging roles: wave -> (tile p, row r); lane -> (kt, g) k-chunk of 8
    const int sp_p = w >> 3, sp_r = w & 7;
    const int sp_kt = lane >> 2, sp_g = lane & 3;
    const size_t xbase = (size_t)(b0 + sp_r) * N_IN + (size_t)lane * 8;  // u32 units
    const int stoff_e = sp_kt * 2048 + sp_p * 1024 + ((sp_g * 256 + sp_r * 16) ^ (sp_kt << 4));
    const int stoff_o = sp_kt * 2048 + sp_p * 1024 + ((sp_g * 256 + (sp_r + 8) * 16) ^ (sp_kt << 4));

    for (int i = tid; i < NOUT * H2S; i += NTH) woL[i] = Wo[i];
    if (tid == 0) s2any = 0;

    const int col0 = w * 32 + l15;   // GEMM1 j for nt=0 (nt=1: +16)
    const int col2 = w * 16 + l15;   // GEMM2 j
    const float b1v0 = b1[col0], b1v1 = b1[col0 + 16];
    const float b2v  = b2[col2];

    float v1[2][4], v2[4];
#pragma unroll
    for (int n = 0; n < 2; ++n)
#pragma unroll
        for (int q = 0; q < 4; ++q) v1[n][q] = 0.0f;
#pragma unroll
    for (int q = 0; q < 4; ++q) v2[q] = 0.0f;
    float vo = 0.0f, osum = 0.0f, bor = (tid < 40) ? bo[tid % 5] : 0.0f;

    const int aoffbase = kg * 256 + l15 * 16;   // A-frag byte offset within a tile
    const int m_q0 = kg * 4;                    // fragment row base

    uint4 xr0, xr1;
    {
        const uint4* g0 = (const uint4*)(xp + (size_t)sp_p * BN + xbase);
        xr0 = g0[0]; xr1 = g0[1];
    }

    for (int q5 = 0; q5 < 25; ++q5) {
        // ---- stage: split (t_even,t_odd) bf16 pairs into xab rows m / m+8 ----
        {
            unsigned int u0 = xr0.x, u1 = xr0.y, u2 = xr0.z, u3 = xr0.w;
            unsigned int u4 = xr1.x, u5 = xr1.y, u6 = xr1.z, u7 = xr1.w;
            uint4 ev, od;
            ev.x = (u0 & 0xffffu) | (u1 << 16);
            ev.y = (u2 & 0xffffu) | (u3 << 16);
            ev.z = (u4 & 0xffffu) | (u5 << 16);
            ev.w = (u6 & 0xffffu) | (u7 << 16);
            od.x = (u0 >> 16) | (u1 & 0xffff0000u);
            od.y = (u2 >> 16) | (u3 & 0xffff0000u);
            od.z = (u4 >> 16) | (u5 & 0xffff0000u);
            od.w = (u6 >> 16) | (u7 & 0xffff0000u);
            *(uint4*)(xab + stoff_e) = ev;
            *(uint4*)(xab + stoff_o) = od;
        }
        __syncthreads();                                   // A

        // prefetch next quad's x into regs (hides HBM latency under GEMMs)
        {
            int prn = (q5 < 24) ? (2 * (q5 + 1) + sp_p) : sp_p;
            const uint4* gn = (const uint4*)(xp + (size_t)prn * BN + xbase);
            xr0 = gn[0]; xr1 = gn[1];
        }

        // ---- GEMM1: acc1[nt][tile], B-frags shared across the two M-tiles ----
        f32x4 acc1[2][2];
#pragma unroll
        for (int n = 0; n < 2; ++n) {
            acc1[n][0] = (f32x4){0.f, 0.f, 0.f, 0.f};
            acc1[n][1] = (f32x4){0.f, 0.f, 0.f, 0.f};
        }
#pragma unroll 4
        for (int kt = 0; kt < 16; ++kt) {
            bf16x8 aA = *(const bf16x8*)(xab + kt * 2048 + (aoffbase ^ (kt << 4)));
            bf16x8 aB = *(const bf16x8*)(xab + kt * 2048 + 1024 + (aoffbase ^ (kt << 4)));
            bf16x8 bw0 = *(const bf16x8*)(W1b + ((size_t)col0 * 512 + kt * 32 + kg * 8));
            bf16x8 bw1 = *(const bf16x8*)(W1b + ((size_t)(col0 + 16) * 512 + kt * 32 + kg * 8));
            acc1[0][0] = __builtin_amdgcn_mfma_f32_16x16x32_bf16(aA, bw0, acc1[0][0], 0, 0, 0);
            acc1[0][1] = __builtin_amdgcn_mfma_f32_16x16x32_bf16(aB, bw0, acc1[0][1], 0, 0, 0);
            acc1[1][0] = __builtin_amdgcn_mfma_f32_16x16x32_bf16(aA, bw1, acc1[1][0], 0, 0, 0);
            acc1[1][1] = __builtin_amdgcn_mfma_f32_16x16x32_bf16(aB, bw1, acc1[1][1], 0, 0, 0);
        }

        // ---- LIF1 in fragment layout -> s1b (bf16) + per-(kt,tile) flags ----
        bool anyA = false, anyB = false;
#pragma unroll
        for (int nt = 0; nt < 2; ++nt) {
            const float bb = nt ? b1v1 : b1v0;
            const int colw = w * 32 + nt * 16 + l15;
            const int kg2 = (colw >> 3) & 3, e2 = colw & 7;
#pragma unroll
            for (int q = 0; q < 4; ++q) {
                float hA = acc1[nt][0][q], hB = acc1[nt][1][q];
                float hxA = __shfl_xor(hA, 32);
                float hxB = __shfl_xor(hB, 32);
                float h0 = glo ? hA : hxA, h1 = glo ? hxA : hA;   // t0, t1
                float h2 = glo ? hB : hxB, h3 = glo ? hxB : hB;   // t2, t3
                float v = v1[nt][q];
                float s0 = lifstep(v, h0 + bb);
                float s1_ = lifstep(v, h1 + bb);
                float s2_ = lifstep(v, h2 + bb);
                float s3_ = lifstep(v, h3 + bb);
                v1[nt][q] = v;
                anyA |= (s0 + s1_) > 0.0f;
                anyB |= (s2_ + s3_) > 0.0f;
                // write own-timestep spikes at own fragment row m
                float ownA = glo ? s0 : s1_;
                float ownB = glo ? s2_ : s3_;
                int m = m_q0 + q;
                int off = w * 2048 + ((kg2 * 256 + m * 16 + e2 * 2) ^ (w << 4));
                *(unsigned short*)(s1b + off)        = (ownA > 0.0f) ? 0x3F80 : 0;
                *(unsigned short*)(s1b + off + 1024) = (ownB > 0.0f) ? 0x3F80 : 0;
            }
        }
        {
            unsigned long long balA = __ballot(anyA);
            unsigned long long balB = __ballot(anyB);
            if (lane == 0)
                flg2[w] = ((balA != 0ULL) ? 1 : 0) | ((balB != 0ULL) ? 2 : 0);
        }
        __syncthreads();                                   // B

        // ---- GEMM2 with per-(kt,tile) spike skip (bit-exact: skipped A==0) ----
        f32x4 acc2[2];
        acc2[0] = (f32x4){0.f, 0.f, 0.f, 0.f};
        acc2[1] = (f32x4){0.f, 0.f, 0.f, 0.f};
        for (int kt = 0; kt < 16; ++kt) {
            const int f = flg2[kt];    // wave-uniform (LDS broadcast)
            if (f) {
                bf16x8 bw = *(const bf16x8*)(W2b + ((size_t)col2 * 512 + kt * 32 + kg * 8));
                if (f & 1) {
                    bf16x8 aA = *(const bf16x8*)(s1b + kt * 2048 + (aoffbase ^ (kt << 4)));
                    acc2[0] = __builtin_amdgcn_mfma_f32_16x16x32_bf16(aA, bw, acc2[0], 0, 0, 0);
                }
                if (f & 2) {
                    bf16x8 aB = *(const bf16x8*)(s1b + kt * 2048 + 1024 + (aoffbase ^ (kt << 4)));
                    acc2[1] = __builtin_amdgcn_mfma_f32_16x16x32_bf16(aB, bw, acc2[1], 0, 0, 0);
                }
            }
        }

        // ---- LIF2 -> s2f (fp32) + s2any ----
        bool any2 = false;
#pragma unroll
        for (int q = 0; q < 4; ++q) {
            float hA = acc2[0][q], hB = acc2[1][q];
            float hxA = __shfl_xor(hA, 32);
            float hxB = __shfl_xor(hB, 32);
            float h0 = glo ? hA : hxA, h1 = glo ? hxA : hA;
            float h2 = glo ? hB : hxB, h3 = glo ? hxB : hB;
            float v = v2[q];
            float s0 = lifstep(v, h0 + b2v);
            float s1_ = lifstep(v, h1 + b2v);
            float s2_ = lifstep(v, h2 + b2v);
            float s3_ = lifstep(v, h3 + b2v);
            v2[q] = v;
            any2 |= (s0 + s1_ + s2_ + s3_) > 0.0f;
            int m = m_q0 + q;
            s2f[m * 256 + col2]        = glo ? s0 : s1_;
            s2f[(16 + m) * 256 + col2] = glo ? s2_ : s3_;
        }
        if (any2) s2any = 1;
        __syncthreads();                                   // C
        const int sk = s2any;

        // ---- GEMM3 + vo LIF (layer 3 exact fp32; usually skipped) ----
        if (sk) {
            if (tid < 160) {
                int m32 = tid / 5, o = tid % 5;
                const float4* s4 = (const float4*)(s2f + m32 * 256);
                const float4* w4 = (const float4*)(woL + o * 256);
                float p = 0.0f;
#pragma unroll
                for (int k = 0; k < 64; ++k) {
                    float4 a = s4[k], ww = w4[k];
                    p += a.x * ww.x + a.y * ww.y + a.z * ww.z + a.w * ww.w;
                }
                ot[tid] = p;
            }
            __syncthreads();                               // D
        }
        if (tid < 40) {
#pragma unroll
            for (int tt = 0; tt < 4; ++tt) {
                float oc = bor + (sk ? ot[tid + tt * 40] : 0.0f);
                float v = vo + (oc - vo) * 0.5f;
                if (v >= 1.0f) { osum += 1.0f; vo = 0.0f; }
                else           { vo = v; }
            }
            if (sk && tid == 0) s2any = 0;   // ordered before next read by barriers A,B
        }
    }

    if (tid < 40) out[(size_t)(b0 + tid / 5) * NOUT + (tid % 5)] = osum / (float)T_STEPS;
}

extern "C" void kernel_launch(void* const* d_in, const int* in_sizes, int n_in,
                              void* d_out, int out_size, void* d_ws, size_t ws_size,
                              hipStream_t stream) {
    const float* x  = (const float*)d_in[0];
    const float* W1 = (const float*)d_in[1];
    const float* b1 = (const float*)d_in[2];
    const float* W2 = (const float*)d_in[3];
    const float* b2 = (const float*)d_in[4];
    const float* Wo = (const float*)d_in[5];
    const float* bo = (const float*)d_in[6];
    float* out = (float*)d_out;

    // ws layout: xp (50*BN u32 = 200MB) | W1b bf16 (512KB) | W2b bf16 (256KB)
    unsigned int* xp = (unsigned int*)d_ws;
    unsigned short* W1b = (unsigned short*)((char*)d_ws + (size_t)50 * BN * 4);
    unsigned short* W2b = W1b + (size_t)H1S * N_IN;

    xpack_kernel<<<BN / 128, 256, 0, stream>>>(x, xp);
    wconv_kernel<<<(H1S * N_IN) / 256, 256, 0, stream>>>(W1, W1b, H1S * N_IN);
    wconv_kernel<<<(H2S * H1S) / 256, 256, 0, stream>>>(W2, W2b, H2S * H1S);
    snn_kernel<<<BB / BT, NTH, 0, stream>>>(xp, W1b, b1, W2b, b2, Wo, bo, out);
}

// Round 8
// 926.342 us; speedup vs baseline: 2.5077x; 1.2565x over previous
//
#include <hip/hip_runtime.h>

// PopulationSNN R7 (third resubmit; GPU broker at capacity 4 rounds running).
// Fix operand-fetch patterns (R6 was bound by B-frag loads touching 64
// cache lines/instr: lanes 1024B apart in j-major W layout).
// - W1/W2 pre-packed to per-wave fragment order: one contiguous 1024B/wave
//   per (j16-group, kt) -> 4x less L2 traffic, 4x fewer line requests.
// - x pre-packed by xfrag directly into the staged-LDS fragment stream
//   xf[q5][blk][kt][tile][1KB]; snn staging = pure linear b128 copy.
// - Numerics identical to R6 (same bf16rne, same MFMA order): bit-exact.

#define T_STEPS 100
#define BB      2048
#define N_IN    512
#define H1S     512
#define H2S     256
#define NOUT    5
#define BT      8
#define NTH     1024
#define BN      (BB * N_IN)   // 1048576

typedef __attribute__((ext_vector_type(8))) short bf16x8;
typedef __attribute__((ext_vector_type(4))) float f32x4;

__device__ __forceinline__ unsigned int bf16rne(float f) {
    unsigned int u = __float_as_uint(f);
    return (u + 0x7fffu + ((u >> 16) & 1u)) >> 16;
}

// ---- xfrag: x:(B,N,T) fp32 -> xf[q5][blk][kt][tile][1KB] bf16 fragment stream ----
// block = (blkb, kt); phase1: per-thread sequential float4 reads (L1 line reuse)
// -> LDS tl2[tp][row] (conflict-free both phases); phase2: b128 LDS reads ->
// coalesced uint4 global stores in final fragment byte order.
__global__ __launch_bounds__(256)
void xfrag_kernel(const float* __restrict__ x, unsigned int* __restrict__ xf) {
    __shared__ unsigned int tl2[50][256];   // [t-pair][row=(r*32+n32)]
    const int bid = blockIdx.x;
    const int blkb = bid >> 4, kt = bid & 15;
    const int b0 = blkb * BT;
    const int tid = threadIdx.x;
    const int r = tid >> 5, n32 = tid & 31;

    const float4* srcp = (const float4*)(x + ((size_t)(b0 + r) * N_IN + kt * 32 + n32) * T_STEPS);
#pragma unroll 5
    for (int f = 0; f < 25; ++f) {
        float4 v = srcp[f];
        tl2[2 * f][tid]     = bf16rne(v.x) | (bf16rne(v.y) << 16);
        tl2[2 * f + 1][tid] = bf16rne(v.z) | (bf16rne(v.w) << 16);
    }
    __syncthreads();

    const int kgm = tid & 63, g = tid >> 6;
    const int kg = kgm >> 4, m = kgm & 15;
    const int hi = m >> 3, rsel = m & 7;
    const int sh = hi * 16;
    const int row0 = rsel * 32 + kg * 8;
    const unsigned int* tlf = &tl2[0][0];

    for (int c = g; c < 50; c += 4) {        // c = q5*2 + tile
        const int q5 = c >> 1, tile = c & 1;
        const uint4* p = (const uint4*)(tlf + c * 256 + row0);
        uint4 qa = p[0], qb = p[1];          // e = 0..3, 4..7
        unsigned int o0 = ((qa.x >> sh) & 0xffffu) | (((qa.y >> sh) & 0xffffu) << 16);
        unsigned int o1 = ((qa.z >> sh) & 0xffffu) | (((qa.w >> sh) & 0xffffu) << 16);
        unsigned int o2 = ((qb.x >> sh) & 0xffffu) | (((qb.y >> sh) & 0xffffu) << 16);
        unsigned int o3 = ((qb.z >> sh) & 0xffffu) | (((qb.w >> sh) & 0xffffu) << 16);
        size_t off = ((((size_t)q5 * 256 + blkb) * 16 + kt) * 2 + tile) * 1024
                   + kg * 256 + m * 16;      // bytes
        *(uint4*)((char*)xf + off) = make_uint4(o0, o1, o2, o3);
    }
}

// ---- wpack: W (R rows x 512 k) fp32 -> Wf[jg][kt] 1024B fragments ----
// byte off within (jg,kt): kg*256 + l15*16 + e*2  (same values a wave loads
// contiguously at lane*16).
__global__ __launch_bounds__(256)
void wpack_kernel(const float* __restrict__ w, unsigned int* __restrict__ wf) {
    const int blk = blockIdx.x;              // blk = jg*16 + kt
    const int jg = blk >> 4, kt = blk & 15;
    const int tid = threadIdx.x;
    const int kg = tid >> 6, l15 = (tid >> 2) & 15, e0 = (tid & 3) * 2;
    const size_t src = (size_t)(jg * 16 + l15) * 512 + kt * 32 + kg * 8 + e0;
    wf[(size_t)blk * 256 + tid] = bf16rne(w[src]) | (bf16rne(w[src + 1]) << 16);
}

__device__ __forceinline__ float lifstep(float& v, float cur) {
    v = v + (cur - v) * 0.5f;
    float s = (v >= 1.0f) ? 1.0f : 0.0f;
    if (v >= 1.0f) v = 0.0f;
    return s;
}

__global__ __launch_bounds__(NTH, 4)
void snn_kernel(const unsigned int* __restrict__ xf,
                const unsigned short* __restrict__ W1f,  // [32 jg][16 kt][512] bf16 frag
                const float* __restrict__ b1,
                const unsigned short* __restrict__ W2f,  // [16 jg][16 kt][512] bf16 frag
                const float* __restrict__ b2,
                const float* __restrict__ Wo,            // (5,256) fp32
                const float* __restrict__ bo,
                float* __restrict__ out)
{
    // M=32 tile: m 0-15 = tile0 (t0 rows 0-7, t1 rows 8-15), m 16-31 = tile1 (t2,t3)
    __shared__ __align__(16) char xab[32768];   // [16 kt][2 tile][1KB], LINEAR (pre-baked)
    __shared__ __align__(16) char s1b[32768];   // same layout, w-XOR swizzled writes
    __shared__ __align__(16) float s2f[32 * 256];
    __shared__ __align__(16) float woL[NOUT * H2S];
    __shared__ float ot[160];
    __shared__ int flg2[16];                    // bit0: tile0 has spikes, bit1: tile1
    __shared__ int s2any;

    const int tid = threadIdx.x;
    const int w = tid >> 6, lane = tid & 63;
    const int l15 = lane & 15, kg = lane >> 4;
    const bool glo = lane < 32;

    for (int i = tid; i < NOUT * H2S; i += NTH) woL[i] = Wo[i];
    if (tid == 0) s2any = 0;

    const int col0 = w * 32 + l15;   // GEMM1 j for nt=0 (nt=1: +16)
    const int col2 = w * 16 + l15;   // GEMM2 j
    const float b1v0 = b1[col0], b1v1 = b1[col0 + 16];
    const float b2v  = b2[col2];

    float v1[2][4], v2[4];
#pragma unroll
    for (int n = 0; n < 2; ++n)
#pragma unroll
        for (int q = 0; q < 4; ++q) v1[n][q] = 0.0f;
#pragma unroll
    for (int q = 0; q < 4; ++q) v2[q] = 0.0f;
    float vo = 0.0f, osum = 0.0f, bor = (tid < 40) ? bo[tid % 5] : 0.0f;

    const int aoff = lane * 16;      // = kg*256 + l15*16 (contiguous per wave)
    const int m_q0 = kg * 4;

    const char* xfp = (const char*)xf;
    uint4 xr0, xr1;
    {
        const size_t c0 = (size_t)blockIdx.x * 32768;
        xr0 = *(const uint4*)(xfp + c0 + tid * 16);
        xr1 = *(const uint4*)(xfp + c0 + 16384 + tid * 16);
    }

    for (int q5 = 0; q5 < 25; ++q5) {
        // ---- stage: pure linear copy (fragment order pre-baked by xfrag) ----
        *(uint4*)(xab + tid * 16)         = xr0;
        *(uint4*)(xab + 16384 + tid * 16) = xr1;
        __syncthreads();                                   // A

        // prefetch next chunk
        {
            const size_t cn = ((size_t)((q5 < 24) ? q5 + 1 : 0) * 256 + blockIdx.x) * 32768;
            xr0 = *(const uint4*)(xfp + cn + tid * 16);
            xr1 = *(const uint4*)(xfp + cn + 16384 + tid * 16);
        }

        // ---- GEMM1: acc1[nt][tile]; W-frags contiguous 1024B per wave ----
        f32x4 acc1[2][2];
#pragma unroll
        for (int n = 0; n < 2; ++n) {
            acc1[n][0] = (f32x4){0.f, 0.f, 0.f, 0.f};
            acc1[n][1] = (f32x4){0.f, 0.f, 0.f, 0.f};
        }
#pragma unroll 4
        for (int kt = 0; kt < 16; ++kt) {
            bf16x8 aA = *(const bf16x8*)(xab + kt * 2048 + aoff);
            bf16x8 aB = *(const bf16x8*)(xab + kt * 2048 + 1024 + aoff);
            bf16x8 bw0 = *(const bf16x8*)(W1f + (((size_t)(w * 2) * 16 + kt) * 512 + lane * 8));
            bf16x8 bw1 = *(const bf16x8*)(W1f + (((size_t)(w * 2 + 1) * 16 + kt) * 512 + lane * 8));
            acc1[0][0] = __builtin_amdgcn_mfma_f32_16x16x32_bf16(aA, bw0, acc1[0][0], 0, 0, 0);
            acc1[0][1] = __builtin_amdgcn_mfma_f32_16x16x32_bf16(aB, bw0, acc1[0][1], 0, 0, 0);
            acc1[1][0] = __builtin_amdgcn_mfma_f32_16x16x32_bf16(aA, bw1, acc1[1][0], 0, 0, 0);
            acc1[1][1] = __builtin_amdgcn_mfma_f32_16x16x32_bf16(aB, bw1, acc1[1][1], 0, 0, 0);
        }

        // ---- LIF1 in fragment layout -> s1b (bf16) + per-(kt,tile) flags ----
        bool anyA = false, anyB = false;
#pragma unroll
        for (int nt = 0; nt < 2; ++nt) {
            const float bb = nt ? b1v1 : b1v0;
            const int colw = w * 32 + nt * 16 + l15;
            const int kg2 = (colw >> 3) & 3, e2 = colw & 7;
#pragma unroll
            for (int q = 0; q < 4; ++q) {
                float hA = acc1[nt][0][q], hB = acc1[nt][1][q];
                float hxA = __shfl_xor(hA, 32);
                float hxB = __shfl_xor(hB, 32);
                float h0 = glo ? hA : hxA, h1 = glo ? hxA : hA;   // t0, t1
                float h2 = glo ? hB : hxB, h3 = glo ? hxB : hB;   // t2, t3
                float v = v1[nt][q];
                float s0 = lifstep(v, h0 + bb);
                float s1_ = lifstep(v, h1 + bb);
                float s2_ = lifstep(v, h2 + bb);
                float s3_ = lifstep(v, h3 + bb);
                v1[nt][q] = v;
                anyA |= (s0 + s1_) > 0.0f;
                anyB |= (s2_ + s3_) > 0.0f;
                float ownA = glo ? s0 : s1_;
                float ownB = glo ? s2_ : s3_;
                int m = m_q0 + q;
                int off = w * 2048 + ((kg2 * 256 + m * 16 + e2 * 2) ^ (w << 4));
                *(unsigned short*)(s1b + off)        = (ownA > 0.0f) ? 0x3F80 : 0;
                *(unsigned short*)(s1b + off + 1024) = (ownB > 0.0f) ? 0x3F80 : 0;
            }
        }
        {
            unsigned long long balA = __ballot(anyA);
            unsigned long long balB = __ballot(anyB);
            if (lane == 0)
                flg2[w] = ((balA != 0ULL) ? 1 : 0) | ((balB != 0ULL) ? 2 : 0);
        }
        __syncthreads();                                   // B

        // ---- GEMM2 with per-(kt,tile) spike skip (bit-exact: skipped A==0) ----
        f32x4 acc2[2];
        acc2[0] = (f32x4){0.f, 0.f, 0.f, 0.f};
        acc2[1] = (f32x4){0.f, 0.f, 0.f, 0.f};
        for (int kt = 0; kt < 16; ++kt) {
            const int f = flg2[kt];    // wave-uniform (LDS broadcast)
            if (f) {
                bf16x8 bw = *(const bf16x8*)(W2f + (((size_t)w * 16 + kt) * 512 + lane * 8));
                if (f & 1) {
                    bf16x8 aA = *(const bf16x8*)(s1b + kt * 2048 + (aoff ^ (kt << 4)));
                    acc2[0] = __builtin_amdgcn_mfma_f32_16x16x32_bf16(aA, bw, acc2[0], 0, 0, 0);
                }
                if (f & 2) {
                    bf16x8 aB = *(const bf16x8*)(s1b + kt * 2048 + 1024 + (aoff ^ (kt << 4)));
                    acc2[1] = __builtin_amdgcn_mfma_f32_16x16x32_bf16(aB, bw, acc2[1], 0, 0, 0);
                }
            }
        }

        // ---- LIF2 -> s2f (fp32) + s2any ----
        bool any2 = false;
#pragma unroll
        for (int q = 0; q < 4; ++q) {
            float hA = acc2[0][q], hB = acc2[1][q];
            float hxA = __shfl_xor(hA, 32);
            float hxB = __shfl_xor(hB, 32);
            float h0 = glo ? hA : hxA, h1 = glo ? hxA : hA;
            float h2 = glo ? hB : hxB, h3 = glo ? hxB : hB;
            float v = v2[q];
            float s0 = lifstep(v, h0 + b2v);
            float s1_ = lifstep(v, h1 + b2v);
            float s2_ = lifstep(v, h2 + b2v);
            float s3_ = lifstep(v, h3 + b2v);
            v2[q] = v;
            any2 |= (s0 + s1_ + s2_ + s3_) > 0.0f;
            int m = m_q0 + q;
            s2f[m * 256 + col2]        = glo ? s0 : s1_;
            s2f[(16 + m) * 256 + col2] = glo ? s2_ : s3_;
        }
        if (any2) s2any = 1;
        __syncthreads();                                   // C
        const int sk = s2any;

        // ---- GEMM3 + vo LIF (layer 3 exact fp32; usually skipped) ----
        if (sk) {
            if (tid < 160) {
                int m32 = tid / 5, o = tid % 5;
                const float4* s4 = (const float4*)(s2f + m32 * 256);
                const float4* w4 = (const float4*)(woL + o * 256);
                float p = 0.0f;
#pragma unroll
                for (int k = 0; k < 64; ++k) {
                    float4 a = s4[k], ww = w4[k];
                    p += a.x * ww.x + a.y * ww.y + a.z * ww.z + a.w * ww.w;
                }
                ot[tid] = p;
            }
            __syncthreads();                               // D
        }
        if (tid < 40) {
#pragma unroll
            for (int tt = 0; tt < 4; ++tt) {
                float oc = bor + (sk ? ot[tid + tt * 40] : 0.0f);
                float v = vo + (oc - vo) * 0.5f;
                if (v >= 1.0f) { osum += 1.0f; vo = 0.0f; }
                else           { vo = v; }
            }
            if (sk && tid == 0) s2any = 0;   // re-ordered vs next read by barriers A,B
        }
    }

    if (tid < 40) out[(size_t)(blockIdx.x * BT + tid / 5) * NOUT + (tid % 5)] = osum / (float)T_STEPS;
}

extern "C" void kernel_launch(void* const* d_in, const int* in_sizes, int n_in,
                              void* d_out, int out_size, void* d_ws, size_t ws_size,
                              hipStream_t stream) {
    const float* x  = (const float*)d_in[0];
    const float* W1 = (const float*)d_in[1];
    const float* b1 = (const float*)d_in[2];
    const float* W2 = (const float*)d_in[3];
    const float* b2 = (const float*)d_in[4];
    const float* Wo = (const float*)d_in[5];
    const float* bo = (const float*)d_in[6];
    float* out = (float*)d_out;

    // ws layout: xf (25*256*32KB = 200MB) | W1f bf16 (512KB) | W2f bf16 (256KB)
    unsigned int* xf = (unsigned int*)d_ws;
    unsigned int* W1f = (unsigned int*)((char*)d_ws + (size_t)50 * BN * 4);
    unsigned int* W2f = W1f + (size_t)H1S * N_IN / 2;

    xfrag_kernel<<<256 * 16, 256, 0, stream>>>(x, xf);
    wpack_kernel<<<(H1S / 16) * 16, 256, 0, stream>>>(W1, W1f);
    wpack_kernel<<<(H2S / 16) * 16, 256, 0, stream>>>(W2, W2f);
    snn_kernel<<<BB / BT, NTH, 0, stream>>>(xf, (const unsigned short*)W1f, b1,
                                            (const unsigned short*)W2f, b2, Wo, bo, out);
}